// Round 19
// baseline (91.993 us; speedup 1.0000x reference)
//
#include <hip/hip_runtime.h>

#define IN_DIM 256
#define OUT_DIM 128
#define SLOPE 0.1f
#define CAP 128   // per-dst bucket capacity; filtered degree ~ Poisson(33), max ~70

typedef short bf16x8 __attribute__((ext_vector_type(8)));
typedef float f32x4  __attribute__((ext_vector_type(4)));
typedef unsigned short ushort4v __attribute__((ext_vector_type(4)));

__device__ __forceinline__ unsigned short f2bf(float f) {
    unsigned u = __builtin_bit_cast(unsigned, f);
    return (unsigned short)((u + 0x7FFFu + ((u >> 16) & 1u)) >> 16);   // RNE
}

// async 16B global->LDS DMA; LDS dest is wave-uniform base + lane*16
__device__ __forceinline__ void gld_lds16(const void* g, void* l) {
    __builtin_amdgcn_global_load_lds(
        (const __attribute__((address_space(1))) void*)g,
        (__attribute__((address_space(3))) void*)l, 16, 0, 0);
}

// ---------------------------------------------------------------------------
// Kernel 0: u = W^T a[0:128], v = W^T a[128:256], cd = b.a_d, cs = b.a_s.
// Tiny (64K MACs, 1 block). Enables score computation from raw feats:
// s_dst[i] = feats[i].u + cd  (linearity of emb in feats).
// ---------------------------------------------------------------------------
__global__ __launch_bounds__(256) void uv_kernel(
    const float* __restrict__ W, const float* __restrict__ a,
    const float* __restrict__ bias, float* __restrict__ uv)
{
    const int k = threadIdx.x;   // 0..255
    float u = 0.f, v = 0.f;
    for (int j = 0; j < OUT_DIM; ++j) {
        const float w = W[(size_t)j * IN_DIM + k];
        u = fmaf(a[j], w, u);
        v = fmaf(a[OUT_DIM + j], w, v);
    }
    uv[k] = u;
    uv[256 + k] = v;
    if (k == 0) {
        float cd = 0.f, cs = 0.f;
        for (int j = 0; j < OUT_DIM; ++j) {
            cd = fmaf(bias[j], a[j], cd);
            cs = fmaf(bias[j], a[OUT_DIM + j], cs);
        }
        uv[512] = cd; uv[513] = cs;
    }
}

// ---------------------------------------------------------------------------
// Kernel 1: fused feats fp32->bf16 convert + s_dst/s_src scores + needed/cur
// init. One wave per row (64 lanes x 4 elems). Pure streaming: 51MB read,
// 25.6MB write. Pad rows [n, npad) get zero fb (deterministic DMA source).
// ---------------------------------------------------------------------------
__global__ __launch_bounds__(256) void cvt_score_kernel(
    const float* __restrict__ feats, const float* __restrict__ uv,
    unsigned short* __restrict__ fb, float* __restrict__ s_dst,
    float* __restrict__ s_src, int* __restrict__ needed,
    int* __restrict__ cur, int n, int npad)
{
    __shared__ float u_s[256], v_s[256];
    const int t    = threadIdx.x;
    const int lane = t & 63;
    const int wid  = t >> 6;
    u_s[t] = uv[t];
    v_s[t] = uv[256 + t];
    __syncthreads();

    const int row = blockIdx.x * 4 + wid;
    if (row >= npad) return;

    if (row < n) {
        const float4 f = *(const float4*)&feats[(size_t)row * IN_DIM + 4 * lane];
        ushort4v o;
        o[0] = f2bf(f.x); o[1] = f2bf(f.y); o[2] = f2bf(f.z); o[3] = f2bf(f.w);
        *(ushort4v*)&fb[(size_t)row * IN_DIM + 4 * lane] = o;

        float sd = f.x * u_s[4*lane]     + f.y * u_s[4*lane + 1]
                 + f.z * u_s[4*lane + 2] + f.w * u_s[4*lane + 3];
        float ss = f.x * v_s[4*lane]     + f.y * v_s[4*lane + 1]
                 + f.z * v_s[4*lane + 2] + f.w * v_s[4*lane + 3];
        #pragma unroll
        for (int o2 = 32; o2 > 0; o2 >>= 1) {
            sd += __shfl_xor(sd, o2);
            ss += __shfl_xor(ss, o2);
        }
        if (lane == 0) {
            s_dst[row] = sd + uv[512];
            s_src[row] = ss + uv[513];
            needed[row] = 0;
            cur[row] = 0;
        }
    } else {
        const ushort4v z = {0, 0, 0, 0};
        *(ushort4v*)&fb[(size_t)row * IN_DIM + 4 * lane] = z;
    }
}

// ---------------------------------------------------------------------------
// Kernel 2: mark needed destinations (plain store; idempotent)
// ---------------------------------------------------------------------------
__global__ void flag_kernel(const int* __restrict__ node_idx,
                            int* __restrict__ needed, int nb)
{
    const int i = blockIdx.x * blockDim.x + threadIdx.x;
    if (i < nb) needed[node_idx[i]] = 1;
}

// ---------------------------------------------------------------------------
// Kernel 3: needed-filtered scatter into per-dst buckets (R7-proven form).
// ---------------------------------------------------------------------------
__global__ __launch_bounds__(256) void scatter_kernel(
    const int* __restrict__ edges, const int* __restrict__ needed,
    int* __restrict__ cur, const float* __restrict__ s_dst,
    const float* __restrict__ s_src, int2* __restrict__ ew, int E)
{
    const int e = blockIdx.x * blockDim.x + threadIdx.x;
    if (e >= E) return;
    const int2 ed = reinterpret_cast<const int2*>(edges)[e];
    if (needed[ed.x]) {
        const float x = s_dst[ed.x] + s_src[ed.y];
        const float w = __expf(x >= 0.f ? x : SLOPE * x);
        const int p = atomicAdd(&cur[ed.x], 1);
        if (p < CAP)
            ew[(size_t)ed.x * CAP + p] = make_int2(ed.y, __float_as_int(w));
    }
}

// ---------------------------------------------------------------------------
// Kernel 4: emb = fb @ W^T + b via bf16 MFMA, BM=64/BK=128, async DMA
// staging of pre-converted bf16 (R13's measured-best staging), 48KB LDS ->
// 3 blocks/CU (R13 was 2). No score epilogue (moved to cvt_score).
// Swizzle on DMA SOURCE chunk, same XOR on fragment read (R13-verified).
// ---------------------------------------------------------------------------
__global__ __launch_bounds__(256) void gemm_mfma_kernel(
    const unsigned short* __restrict__ fb, const float* __restrict__ W,
    const float* __restrict__ bias, unsigned short* __restrict__ emb_bf,
    int n)
{
    __shared__ __align__(16) unsigned short A_s[64 * 128];    // 16KB
    __shared__ __align__(16) unsigned short W_s[128 * 128];   // 32KB

    const int t    = threadIdx.x;
    const int lane = t & 63;
    const int wid  = t >> 6;
    const int wr   = wid >> 1;          // 0..1 : 32-row half
    const int wc   = wid & 1;           // 0..1 : 64-col half
    const int row0 = blockIdx.x * 64;

    const int rlo = lane >> 4;    // row within 4-row DMA slot
    const int cA  = lane & 15;    // 16B chunk within 256B row

    const f32x4 z4 = {0.f, 0.f, 0.f, 0.f};
    f32x4 acc[2][4];
    #pragma unroll
    for (int mi = 0; mi < 2; ++mi)
        #pragma unroll
        for (int ni = 0; ni < 4; ++ni) acc[mi][ni] = z4;

    for (int ph = 0; ph < 2; ++ph) {
        const int k0 = ph * 128;
        if (ph) __syncthreads();

        // ---- A: 4 DMA issues/wave (64 rows x 256B bf16) ----
        #pragma unroll
        for (int j = 0; j < 4; ++j) {
            const int slot = wid * 4 + j;          // 0..15
            const int r    = slot * 4 + rlo;       // 0..63 (fb padded: always valid)
            const int ch   = cA ^ (r & 7);         // pre-swizzled source chunk
            gld_lds16(fb + (size_t)(row0 + r) * IN_DIM + k0 + (ch << 3),
                      &A_s[slot * 512]);
        }
        // ---- W: 8 DMA issues/wave (128 rows x 256B, fp32->16B chunks) ----
        // W staged as bf16? W is fp32 in global; stage via VGPR once is cheap
        // relative, but DMA requires bytes verbatim. Instead DMA fp32 W would
        // need 64KB. Convert W through registers (128KB only, L2-hot):
        #pragma unroll
        for (int j = 0; j < 2; ++j) {
            const int g = j * 256 + t;             // 0..511
            const int r = g >> 2;                  // W row 0..127
            const int c = g & 3;                   // 32-elem quarter
            const float4 v0 = *(const float4*)&W[(size_t)r * IN_DIM + k0 + c * 32 + 0];
            const float4 v1 = *(const float4*)&W[(size_t)r * IN_DIM + k0 + c * 32 + 4];
            const float4 v2 = *(const float4*)&W[(size_t)r * IN_DIM + k0 + c * 32 + 8];
            const float4 v3 = *(const float4*)&W[(size_t)r * IN_DIM + k0 + c * 32 + 12];
            const float4 v4 = *(const float4*)&W[(size_t)r * IN_DIM + k0 + c * 32 + 16];
            const float4 v5 = *(const float4*)&W[(size_t)r * IN_DIM + k0 + c * 32 + 20];
            const float4 v6 = *(const float4*)&W[(size_t)r * IN_DIM + k0 + c * 32 + 24];
            const float4 v7 = *(const float4*)&W[(size_t)r * IN_DIM + k0 + c * 32 + 28];
            bf16x8 p0, p1, p2, p3;
            p0[0]=(short)f2bf(v0.x); p0[1]=(short)f2bf(v0.y); p0[2]=(short)f2bf(v0.z); p0[3]=(short)f2bf(v0.w);
            p0[4]=(short)f2bf(v1.x); p0[5]=(short)f2bf(v1.y); p0[6]=(short)f2bf(v1.z); p0[7]=(short)f2bf(v1.w);
            p1[0]=(short)f2bf(v2.x); p1[1]=(short)f2bf(v2.y); p1[2]=(short)f2bf(v2.z); p1[3]=(short)f2bf(v2.w);
            p1[4]=(short)f2bf(v3.x); p1[5]=(short)f2bf(v3.y); p1[6]=(short)f2bf(v3.z); p1[7]=(short)f2bf(v3.w);
            p2[0]=(short)f2bf(v4.x); p2[1]=(short)f2bf(v4.y); p2[2]=(short)f2bf(v4.z); p2[3]=(short)f2bf(v4.w);
            p2[4]=(short)f2bf(v5.x); p2[5]=(short)f2bf(v5.y); p2[6]=(short)f2bf(v5.z); p2[7]=(short)f2bf(v5.w);
            p3[0]=(short)f2bf(v6.x); p3[1]=(short)f2bf(v6.y); p3[2]=(short)f2bf(v6.z); p3[3]=(short)f2bf(v6.w);
            p3[4]=(short)f2bf(v7.x); p3[5]=(short)f2bf(v7.y); p3[6]=(short)f2bf(v7.z); p3[7]=(short)f2bf(v7.w);
            const int cb = c * 4;                  // base 16B chunk (4 per quarter)
            *(bf16x8*)&W_s[(r * 128) + (((cb + 0) ^ (r & 7)) << 3)] = p0;
            *(bf16x8*)&W_s[(r * 128) + (((cb + 1) ^ (r & 7)) << 3)] = p1;
            *(bf16x8*)&W_s[(r * 128) + (((cb + 2) ^ (r & 7)) << 3)] = p2;
            *(bf16x8*)&W_s[(r * 128) + (((cb + 3) ^ (r & 7)) << 3)] = p3;
        }
        __syncthreads();   // drains vmcnt -> A tile complete; W stores done

        // ---- compute: 4 K-steps of 32 ----
        #pragma unroll
        for (int ks = 0; ks < 4; ++ks) {
            const int kf = ks * 32 + (lane >> 4) * 8;
            bf16x8 af[2], wf[4];
            #pragma unroll
            for (int mi = 0; mi < 2; ++mi) {
                const int row = wr * 32 + mi * 16 + (lane & 15);
                const int off = (row * 128 + kf) ^ ((row & 7) << 3);
                af[mi] = *(const bf16x8*)&A_s[off];
            }
            #pragma unroll
            for (int ni = 0; ni < 4; ++ni) {
                const int col = wc * 64 + ni * 16 + (lane & 15);
                const int off = (col * 128 + kf) ^ ((col & 7) << 3);
                wf[ni] = *(const bf16x8*)&W_s[off];
            }
            #pragma unroll
            for (int mi = 0; mi < 2; ++mi)
                #pragma unroll
                for (int ni = 0; ni < 4; ++ni)
                    acc[mi][ni] = __builtin_amdgcn_mfma_f32_16x16x32_bf16(
                        af[mi], wf[ni], acc[mi][ni], 0, 0, 0);
        }
    }

    // ---- epilogue: bias + bf16 emb store ----
    float bcol[4];
    #pragma unroll
    for (int ni = 0; ni < 4; ++ni)
        bcol[ni] = bias[wc * 64 + ni * 16 + (lane & 15)];

    #pragma unroll
    for (int mi = 0; mi < 2; ++mi) {
        #pragma unroll
        for (int j = 0; j < 4; ++j) {
            const int row = row0 + wr * 32 + mi * 16 + (lane >> 4) * 4 + j;
            if (row < n) {
                #pragma unroll
                for (int ni = 0; ni < 4; ++ni) {
                    const float v = acc[mi][ni][j] + bcol[ni];
                    emb_bf[(size_t)row * OUT_DIM + wc * 64 + ni * 16 + (lane & 15)] = f2bf(v);
                }
            }
        }
    }
}

// ---------------------------------------------------------------------------
// Kernel 5: fused aggregate + output (R7-proven form).
// ---------------------------------------------------------------------------
__global__ __launch_bounds__(256) void agg_out_kernel(
    const int* __restrict__ node_idx, const int* __restrict__ cur,
    const int2* __restrict__ ew, const unsigned short* __restrict__ emb_bf,
    float* __restrict__ out, int nb)
{
    const int w    = (int)((blockIdx.x * blockDim.x + threadIdx.x) >> 6);
    const int lane = threadIdx.x & 63;
    if (w >= nb) return;

    const int dst = node_idx[w];
    int m = cur[dst];
    if (m > CAP) m = CAP;
    const int2* __restrict__ bucket = ew + (size_t)dst * CAP;

    float accx = 0.f, accy = 0.f, den = 0.f;

    for (int base = 0; base < m; base += 64) {
        const int rem = min(64, m - base);
        int   src = 0;
        float wt  = 0.f;
        if (lane < rem) {
            const int2 q = bucket[base + lane];
            src = q.x;
            wt  = __int_as_float(q.y);
        }
        int i = 0;
        for (; i + 4 <= rem; i += 4) {
            const int   s0 = __shfl(src, i),     s1 = __shfl(src, i + 1);
            const int   s2 = __shfl(src, i + 2), s3 = __shfl(src, i + 3);
            const float w0 = __shfl(wt, i),      w1 = __shfl(wt, i + 1);
            const float w2 = __shfl(wt, i + 2),  w3 = __shfl(wt, i + 3);
            const unsigned b0 = *(const unsigned*)&emb_bf[(size_t)s0 * OUT_DIM + 2 * lane];
            const unsigned b1 = *(const unsigned*)&emb_bf[(size_t)s1 * OUT_DIM + 2 * lane];
            const unsigned b2 = *(const unsigned*)&emb_bf[(size_t)s2 * OUT_DIM + 2 * lane];
            const unsigned b3 = *(const unsigned*)&emb_bf[(size_t)s3 * OUT_DIM + 2 * lane];
            den += (w0 + w1) + (w2 + w3);
            accx = fmaf(w0, __int_as_float((int)(b0 << 16)), accx);
            accy = fmaf(w0, __int_as_float((int)(b0 & 0xFFFF0000u)), accy);
            accx = fmaf(w1, __int_as_float((int)(b1 << 16)), accx);
            accy = fmaf(w1, __int_as_float((int)(b1 & 0xFFFF0000u)), accy);
            accx = fmaf(w2, __int_as_float((int)(b2 << 16)), accx);
            accy = fmaf(w2, __int_as_float((int)(b2 & 0xFFFF0000u)), accy);
            accx = fmaf(w3, __int_as_float((int)(b3 << 16)), accx);
            accy = fmaf(w3, __int_as_float((int)(b3 & 0xFFFF0000u)), accy);
        }
        for (; i < rem; ++i) {
            const int   s0 = __shfl(src, i);
            const float w0 = __shfl(wt, i);
            const unsigned b0 = *(const unsigned*)&emb_bf[(size_t)s0 * OUT_DIM + 2 * lane];
            den += w0;
            accx = fmaf(w0, __int_as_float((int)(b0 << 16)), accx);
            accy = fmaf(w0, __int_as_float((int)(b0 & 0xFFFF0000u)), accy);
        }
    }

    const float inv = 1.0f / den;
    float2 o; o.x = accx * inv; o.y = accy * inv;
    *reinterpret_cast<float2*>(&out[(size_t)w * OUT_DIM + 2 * lane]) = o;
}

// ---------------------------------------------------------------------------
extern "C" void kernel_launch(void* const* d_in, const int* in_sizes, int n_in,
                              void* d_out, int out_size, void* d_ws, size_t ws_size,
                              hipStream_t stream)
{
    const float* feats    = (const float*)d_in[0];
    const float* W        = (const float*)d_in[1];
    const float* bias     = (const float*)d_in[2];
    const float* a        = (const float*)d_in[3];
    const int*   edges    = (const int*)d_in[4];
    const int*   node_idx = (const int*)d_in[5];
    float*       out      = (float*)d_out;

    const int n  = in_sizes[0] / IN_DIM;   // 50000
    const int E  = in_sizes[4] / 2;        // 1650000
    const int nb = in_sizes[5];            // 10000
    const int npad = ((n + 63) / 64) * 64; // 50048

    // Workspace layout (16B-aligned segments):
    char* ws = (char*)d_ws;
    unsigned short* emb_bf = (unsigned short*)ws;
    ws += (size_t)n * OUT_DIM * sizeof(unsigned short);                   // 12.8 MB
    unsigned short* fb = (unsigned short*)ws;
    ws += (size_t)npad * IN_DIM * sizeof(unsigned short);                 // 25.6 MB
    float* s_dst = (float*)ws;  ws += (size_t)(n + 4) * sizeof(float);
    float* s_src = (float*)ws;  ws += (size_t)(n + 4) * sizeof(float);
    int*   needed= (int*)ws;    ws += (size_t)(n + 4) * sizeof(int);
    int*   cur   = (int*)ws;    ws += (size_t)(n + 4) * sizeof(int);
    float* uv    = (float*)ws;  ws += 516 * sizeof(float);
    int2*  ew    = (int2*)ws;   ws += (size_t)n * CAP * sizeof(int2);     // 51.2 MB

    uv_kernel       <<<1, 256, 0, stream>>>(W, a, bias, uv);
    cvt_score_kernel<<<npad / 4, 256, 0, stream>>>(feats, uv, fb, s_dst, s_src, needed, cur, n, npad);
    flag_kernel     <<<(nb + 255) / 256, 256, 0, stream>>>(node_idx, needed, nb);
    scatter_kernel  <<<(E + 255) / 256, 256, 0, stream>>>(edges, needed, cur, s_dst, s_src, ew, E);
    gemm_mfma_kernel<<<npad / 64, 256, 0, stream>>>(fb, W, bias, emb_bf, n);
    agg_out_kernel  <<<(nb + 3) / 4, 256, 0, stream>>>(node_idx, cur, ew, emb_bf, out, nb);
}

// Round 20
// 63.594 us; speedup vs baseline: 1.4466x; 1.4466x over previous
//
#include <hip/hip_runtime.h>

#define IN_DIM 256
#define OUT_DIM 128
#define SLOPE 0.1f
#define CAP 128   // per-dst bucket capacity; filtered degree ~ Poisson(33), max ~70

typedef short bf16x8 __attribute__((ext_vector_type(8)));
typedef float f32x4  __attribute__((ext_vector_type(4)));

__device__ __forceinline__ unsigned short f2bf(float f) {
    unsigned u = __builtin_bit_cast(unsigned, f);
    return (unsigned short)((u + 0x7FFFu + ((u >> 16) & 1u)) >> 16);   // RNE
}

__device__ __forceinline__ void pack8(const float4& v0, const float4& v1, bf16x8& pk) {
    pk[0]=(short)f2bf(v0.x); pk[1]=(short)f2bf(v0.y);
    pk[2]=(short)f2bf(v0.z); pk[3]=(short)f2bf(v0.w);
    pk[4]=(short)f2bf(v1.x); pk[5]=(short)f2bf(v1.y);
    pk[6]=(short)f2bf(v1.z); pk[7]=(short)f2bf(v1.w);
}

// ---------------------------------------------------------------------------
// Kernel 1: emb = feats @ W^T + b via bf16 MFMA, BM=128, 256 threads.
// Session-best form (R15, 63.30us total). Gemm runs at ~86 TF = the guide's
// measured shape-curve level for K=256 (small-K staging:compute bound) —
// 7 structural variants all land 35-41us. Fused: s_dst/s_src scores;
// needed[]/cur[] init; emb stored bf16.
// ---------------------------------------------------------------------------
__global__ __launch_bounds__(256, 2) void gemm_mfma_kernel(
    const float* __restrict__ feats, const float* __restrict__ W,
    const float* __restrict__ bias, const float* __restrict__ a,
    unsigned short* __restrict__ emb_bf, float* __restrict__ s_dst,
    float* __restrict__ s_src, int* __restrict__ needed,
    int* __restrict__ cur, int n)
{
    __shared__ __align__(16) unsigned short A_s[128 * 128];
    __shared__ __align__(16) unsigned short W_s[128 * 128];
    __shared__ float sd_l[2][128];
    __shared__ float ss_l[2][128];

    const int t    = threadIdx.x;
    const int lane = t & 63;
    const int wid  = t >> 6;
    const int wr   = wid >> 1;
    const int wc   = wid & 1;
    const int row0 = blockIdx.x * 128;

    if (t < 128) {
        const int ci = row0 + t;
        if (ci < n) { needed[ci] = 0; cur[ci] = 0; }
    }

    const int tr = t >> 4;
    const int tc = t & 15;

    const bool full = (row0 + 128 <= n);

    const f32x4 z4 = {0.f, 0.f, 0.f, 0.f};
    f32x4 acc[4][4];
    #pragma unroll
    for (int mi = 0; mi < 4; ++mi)
        #pragma unroll
        for (int ni = 0; ni < 4; ++ni) acc[mi][ni] = z4;

    for (int ph = 0; ph < 2; ++ph) {
        const int k0 = ph * 128;
        if (ph) __syncthreads();

        if (full) {
            {
                const float* pa = &feats[(size_t)(row0 + tr) * IN_DIM + k0 + tc * 8];
                float4 b0[4], b1[4];
                #pragma unroll
                for (int i = 0; i < 4; ++i) {
                    b0[i] = *(const float4*)(pa + (size_t)i * 16 * IN_DIM);
                    b1[i] = *(const float4*)(pa + (size_t)i * 16 * IN_DIM + 4);
                }
                #pragma unroll
                for (int i = 0; i < 8; ++i) {
                    const int r = i * 16 + tr;
                    bf16x8 pk; pack8(b0[i & 3], b1[i & 3], pk);
                    const int off = (r * 128 + tc * 8) ^ ((r & 7) << 3);
                    *(bf16x8*)&A_s[off] = pk;
                    if (i + 4 < 8) {
                        b0[i & 3] = *(const float4*)(pa + (size_t)(i + 4) * 16 * IN_DIM);
                        b1[i & 3] = *(const float4*)(pa + (size_t)(i + 4) * 16 * IN_DIM + 4);
                    }
                }
            }
            {
                const float* pw = &W[(size_t)tr * IN_DIM + k0 + tc * 8];
                float4 b0[4], b1[4];
                #pragma unroll
                for (int i = 0; i < 4; ++i) {
                    b0[i] = *(const float4*)(pw + (size_t)i * 16 * IN_DIM);
                    b1[i] = *(const float4*)(pw + (size_t)i * 16 * IN_DIM + 4);
                }
                #pragma unroll
                for (int i = 0; i < 8; ++i) {
                    const int r = i * 16 + tr;
                    bf16x8 pk; pack8(b0[i & 3], b1[i & 3], pk);
                    const int off = (r * 128 + tc * 8) ^ ((r & 7) << 3);
                    *(bf16x8*)&W_s[off] = pk;
                    if (i + 4 < 8) {
                        b0[i & 3] = *(const float4*)(pw + (size_t)(i + 4) * 16 * IN_DIM);
                        b1[i & 3] = *(const float4*)(pw + (size_t)(i + 4) * 16 * IN_DIM + 4);
                    }
                }
            }
        } else {
            #pragma unroll
            for (int i = 0; i < 8; ++i) {
                const int r = i * 16 + tr;
                const int gr = row0 + r;
                float4 v0 = make_float4(0.f, 0.f, 0.f, 0.f), v1 = v0;
                if (gr < n) {
                    const float* p = &feats[(size_t)gr * IN_DIM + k0 + tc * 8];
                    v0 = *(const float4*)p;
                    v1 = *(const float4*)(p + 4);
                }
                bf16x8 pk; pack8(v0, v1, pk);
                const int off = (r * 128 + tc * 8) ^ ((r & 7) << 3);
                *(bf16x8*)&A_s[off] = pk;
            }
            #pragma unroll
            for (int i = 0; i < 8; ++i) {
                const int r = i * 16 + tr;
                const float* p = &W[(size_t)r * IN_DIM + k0 + tc * 8];
                const float4 v0 = *(const float4*)p;
                const float4 v1 = *(const float4*)(p + 4);
                bf16x8 pk; pack8(v0, v1, pk);
                const int off = (r * 128 + tc * 8) ^ ((r & 7) << 3);
                *(bf16x8*)&W_s[off] = pk;
            }
        }
        __syncthreads();

        #pragma unroll
        for (int ks = 0; ks < 4; ++ks) {
            const int kf = ks * 32 + (lane >> 4) * 8;
            bf16x8 af[4], wf[4];
            #pragma unroll
            for (int mi = 0; mi < 4; ++mi) {
                const int row = wr * 64 + mi * 16 + (lane & 15);
                const int off = (row * 128 + kf) ^ ((row & 7) << 3);
                af[mi] = *(const bf16x8*)&A_s[off];
            }
            #pragma unroll
            for (int ni = 0; ni < 4; ++ni) {
                const int col = wc * 64 + ni * 16 + (lane & 15);
                const int off = (col * 128 + kf) ^ ((col & 7) << 3);
                wf[ni] = *(const bf16x8*)&W_s[off];
            }
            #pragma unroll
            for (int mi = 0; mi < 4; ++mi)
                #pragma unroll
                for (int ni = 0; ni < 4; ++ni)
                    acc[mi][ni] = __builtin_amdgcn_mfma_f32_16x16x32_bf16(
                        af[mi], wf[ni], acc[mi][ni], 0, 0, 0);
        }
    }

    float bcol[4], avd[4], avs[4];
    #pragma unroll
    for (int ni = 0; ni < 4; ++ni) {
        const int col = wc * 64 + ni * 16 + (lane & 15);
        bcol[ni] = bias[col];
        avd[ni]  = a[col];
        avs[ni]  = a[OUT_DIM + col];
    }

    #pragma unroll
    for (int mi = 0; mi < 4; ++mi) {
        #pragma unroll
        for (int j = 0; j < 4; ++j) {
            const int rib = wr * 64 + mi * 16 + (lane >> 4) * 4 + j;
            const int row = row0 + rib;
            float pd = 0.f, ps = 0.f;
            if (row < n) {
                #pragma unroll
                for (int ni = 0; ni < 4; ++ni) {
                    const float v = acc[mi][ni][j] + bcol[ni];
                    emb_bf[(size_t)row * OUT_DIM + wc * 64 + ni * 16 + (lane & 15)] = f2bf(v);
                    pd = fmaf(v, avd[ni], pd);
                    ps = fmaf(v, avs[ni], ps);
                }
            }
            pd += __shfl_xor(pd, 1); ps += __shfl_xor(ps, 1);
            pd += __shfl_xor(pd, 2); ps += __shfl_xor(ps, 2);
            pd += __shfl_xor(pd, 4); ps += __shfl_xor(ps, 4);
            pd += __shfl_xor(pd, 8); ps += __shfl_xor(ps, 8);
            if ((lane & 15) == 0) { sd_l[wc][rib] = pd; ss_l[wc][rib] = ps; }
        }
    }
    __syncthreads();
    if (t < 128) {
        const int row = row0 + t;
        if (row < n) {
            s_dst[row] = sd_l[0][t] + sd_l[1][t];
            s_src[row] = ss_l[0][t] + ss_l[1][t];
        }
    }
}

// ---------------------------------------------------------------------------
// Kernel 2: mark needed destinations (plain store; idempotent)
// ---------------------------------------------------------------------------
__global__ void flag_kernel(const int* __restrict__ node_idx,
                            int* __restrict__ needed, int nb)
{
    const int i = blockIdx.x * blockDim.x + threadIdx.x;
    if (i < nb) needed[node_idx[i]] = 1;
}

// ---------------------------------------------------------------------------
// Kernel 3: needed-filtered scatter into per-dst buckets (R7-proven form).
// Filter suppresses ~86MB write-allocate traffic + 1.35M atomics (R8 lesson).
// ---------------------------------------------------------------------------
__global__ __launch_bounds__(256) void scatter_kernel(
    const int* __restrict__ edges, const int* __restrict__ needed,
    int* __restrict__ cur, const float* __restrict__ s_dst,
    const float* __restrict__ s_src, int2* __restrict__ ew, int E)
{
    const int e = blockIdx.x * blockDim.x + threadIdx.x;
    if (e >= E) return;
    const int2 ed = reinterpret_cast<const int2*>(edges)[e];
    if (needed[ed.x]) {
        const float x = s_dst[ed.x] + s_src[ed.y];
        const float w = __expf(x >= 0.f ? x : SLOPE * x);
        const int p = atomicAdd(&cur[ed.x], 1);
        if (p < CAP)
            ew[(size_t)ed.x * CAP + p] = make_int2(ed.y, __float_as_int(w));
    }
}

// ---------------------------------------------------------------------------
// Kernel 4: fused aggregate + output (R7-proven form; R18 A/B showed agg is
// L3-BW-bound at ~7 TB/s — splitting the gather chain is neutral).
// ---------------------------------------------------------------------------
__global__ __launch_bounds__(256) void agg_out_kernel(
    const int* __restrict__ node_idx, const int* __restrict__ cur,
    const int2* __restrict__ ew, const unsigned short* __restrict__ emb_bf,
    float* __restrict__ out, int nb)
{
    const int w    = (int)((blockIdx.x * blockDim.x + threadIdx.x) >> 6);
    const int lane = threadIdx.x & 63;
    if (w >= nb) return;

    const int dst = node_idx[w];
    int m = cur[dst];
    if (m > CAP) m = CAP;
    const int2* __restrict__ bucket = ew + (size_t)dst * CAP;

    float accx = 0.f, accy = 0.f, den = 0.f;

    for (int base = 0; base < m; base += 64) {
        const int rem = min(64, m - base);
        int   src = 0;
        float wt  = 0.f;
        if (lane < rem) {
            const int2 q = bucket[base + lane];
            src = q.x;
            wt  = __int_as_float(q.y);
        }
        int i = 0;
        for (; i + 4 <= rem; i += 4) {
            const int   s0 = __shfl(src, i),     s1 = __shfl(src, i + 1);
            const int   s2 = __shfl(src, i + 2), s3 = __shfl(src, i + 3);
            const float w0 = __shfl(wt, i),      w1 = __shfl(wt, i + 1);
            const float w2 = __shfl(wt, i + 2),  w3 = __shfl(wt, i + 3);
            const unsigned b0 = *(const unsigned*)&emb_bf[(size_t)s0 * OUT_DIM + 2 * lane];
            const unsigned b1 = *(const unsigned*)&emb_bf[(size_t)s1 * OUT_DIM + 2 * lane];
            const unsigned b2 = *(const unsigned*)&emb_bf[(size_t)s2 * OUT_DIM + 2 * lane];
            const unsigned b3 = *(const unsigned*)&emb_bf[(size_t)s3 * OUT_DIM + 2 * lane];
            den += (w0 + w1) + (w2 + w3);
            accx = fmaf(w0, __int_as_float((int)(b0 << 16)), accx);
            accy = fmaf(w0, __int_as_float((int)(b0 & 0xFFFF0000u)), accy);
            accx = fmaf(w1, __int_as_float((int)(b1 << 16)), accx);
            accy = fmaf(w1, __int_as_float((int)(b1 & 0xFFFF0000u)), accy);
            accx = fmaf(w2, __int_as_float((int)(b2 << 16)), accx);
            accy = fmaf(w2, __int_as_float((int)(b2 & 0xFFFF0000u)), accy);
            accx = fmaf(w3, __int_as_float((int)(b3 << 16)), accx);
            accy = fmaf(w3, __int_as_float((int)(b3 & 0xFFFF0000u)), accy);
        }
        for (; i < rem; ++i) {
            const int   s0 = __shfl(src, i);
            const float w0 = __shfl(wt, i);
            const unsigned b0 = *(const unsigned*)&emb_bf[(size_t)s0 * OUT_DIM + 2 * lane];
            den += w0;
            accx = fmaf(w0, __int_as_float((int)(b0 << 16)), accx);
            accy = fmaf(w0, __int_as_float((int)(b0 & 0xFFFF0000u)), accy);
        }
    }

    const float inv = 1.0f / den;
    float2 o; o.x = accx * inv; o.y = accy * inv;
    *reinterpret_cast<float2*>(&out[(size_t)w * OUT_DIM + 2 * lane]) = o;
}

// ---------------------------------------------------------------------------
extern "C" void kernel_launch(void* const* d_in, const int* in_sizes, int n_in,
                              void* d_out, int out_size, void* d_ws, size_t ws_size,
                              hipStream_t stream)
{
    const float* feats    = (const float*)d_in[0];
    const float* W        = (const float*)d_in[1];
    const float* bias     = (const float*)d_in[2];
    const float* a        = (const float*)d_in[3];
    const int*   edges    = (const int*)d_in[4];
    const int*   node_idx = (const int*)d_in[5];
    float*       out      = (float*)d_out;

    const int n  = in_sizes[0] / IN_DIM;   // 50000
    const int E  = in_sizes[4] / 2;        // 1650000
    const int nb = in_sizes[5];            // 10000

    // Workspace layout (16B-aligned segments):
    char* ws = (char*)d_ws;
    unsigned short* emb_bf = (unsigned short*)ws;
    ws += (size_t)n * OUT_DIM * sizeof(unsigned short);                 // 12.8 MB
    float* s_dst = (float*)ws;  ws += (size_t)(n + 4) * sizeof(float);
    float* s_src = (float*)ws;  ws += (size_t)(n + 4) * sizeof(float);
    int*   needed= (int*)ws;    ws += (size_t)(n + 4) * sizeof(int);
    int*   cur   = (int*)ws;    ws += (size_t)(n + 4) * sizeof(int);
    int2*  ew    = (int2*)ws;   ws += (size_t)n * CAP * sizeof(int2);   // 51.2 MB

    gemm_mfma_kernel<<<(n + 127) / 128, 256, 0, stream>>>(
        feats, W, bias, a, emb_bf, s_dst, s_src, needed, cur, n);
    flag_kernel     <<<(nb + 255) / 256, 256, 0, stream>>>(node_idx, needed, nb);
    scatter_kernel  <<<(E + 255) / 256, 256, 0, stream>>>(edges, needed, cur, s_dst, s_src, ew, E);
    agg_out_kernel  <<<(nb + 3) / 4, 256, 0, stream>>>(node_idx, cur, ew, emb_bf, out, nb);
}